// Round 1
// baseline (600.273 us; speedup 1.0000x reference)
//
#include <hip/hip_runtime.h>

// Problem dims
#define TOK   16384   // B*S
#define INFT  2048
#define HID   1024
#define CBD   32
#define NC    256
#define OUTF  2048

// ---------------------------------------------------------------------------
// ws layout (float offsets)
//  up_wT   : [1024][2048]            @ 0          (2,097,152)
//  partial : [16][32][2048]          @ 2097152    (1,048,576)  (reused twice)
//  WfT     : [2048][32]  (i-major)   @ 3145728    (65,536)
//  U2c     : [32][2048]  (c-major)   @ 3211264    (65,536)
//  bf      : [32]                    @ 3276800
//  b2      : [2048]                  @ 3276832
//  T       : [256][2048]             @ 3278880    (524,288)
//  idx     : [16384] int             @ 3803168
// total ~14.6 MB
#define WS_UPWT   0
#define WS_PART   2097152
#define WS_WFT    3145728
#define WS_U2C    3211264
#define WS_BF     3276800
#define WS_B2     3276832
#define WS_T      3278880
#define WS_IDX    3803168

// ---------------------------------------------------------------------------
// Transpose up_w [2048][1024] -> up_wT [1024][2048]
__global__ void kt_transpose(const float* __restrict__ up_w, float* __restrict__ up_wT) {
    __shared__ float tile[32][33];
    int h0 = blockIdx.x * 32;            // over HID
    int o0 = blockIdx.y * 32;            // over OUTF
    int tx = threadIdx.x & 31, ty = threadIdx.x >> 5;   // 32x8
    #pragma unroll
    for (int j = 0; j < 32; j += 8)
        tile[ty + j][tx] = up_w[(o0 + ty + j) * HID + h0 + tx];
    __syncthreads();
    #pragma unroll
    for (int j = 0; j < 32; j += 8)
        up_wT[(h0 + ty + j) * OUTF + o0 + tx] = tile[tx][ty + j];
}

// ---------------------------------------------------------------------------
// Fused weight partial: part[kc][c][2048] = sum_{k in chunk} lhs(c,k) * rhs[k][i]
// lhs element at lhs[c*lhsSC + k*lhsSK]  (uniform address -> s_load)
__global__ void k_fuse_partial(const float* __restrict__ lhs, const float* __restrict__ rhs,
                               float* __restrict__ part, int lhsSC, int lhsSK) {
    int i  = blockIdx.x * 256 + threadIdx.x;
    int k0 = blockIdx.y * 64;
    float acc[32];
    #pragma unroll
    for (int c = 0; c < 32; c++) acc[c] = 0.f;
    for (int j = 0; j < 64; j++) {
        float xv = rhs[(k0 + j) * 2048 + i];
        #pragma unroll
        for (int c = 0; c < 32; c++)
            acc[c] = fmaf(lhs[c * lhsSC + (k0 + j) * lhsSK], xv, acc[c]);
    }
    #pragma unroll
    for (int c = 0; c < 32; c++)
        part[(blockIdx.y * 32 + c) * 2048 + i] = acc[c];
}

// Reduce 16 partials -> outw[i*outSI + c*outSC]
__global__ void k_fuse_reduce(const float* __restrict__ part, float* __restrict__ outw,
                              int outSI, int outSC) {
    int f = blockIdx.x * 256 + threadIdx.x;   // 0..65535
    int i = f & 2047, c = f >> 11;
    float s = 0.f;
    #pragma unroll
    for (int b = 0; b < 16; b++) s += part[b * 65536 + c * 2048 + i];
    outw[i * outSI + c * outSC] = s;
}

// bf[c] = pin_b[c] + sum_k pin_w[c][k] * down_b[k]      (grid=1, block=256)
__global__ void k_bias_f(const float* __restrict__ pin_w, const float* __restrict__ pin_b,
                         const float* __restrict__ down_b, float* __restrict__ bf) {
    __shared__ float red[256];
    int c = threadIdx.x >> 3, seg = threadIdx.x & 7;
    float s = 0.f;
    for (int k = seg * 128; k < seg * 128 + 128; k++)
        s = fmaf(pin_w[c * HID + k], down_b[k], s);
    red[threadIdx.x] = s;
    __syncthreads();
    if (threadIdx.x < 32) {
        float t = pin_b[threadIdx.x];
        #pragma unroll
        for (int q = 0; q < 8; q++) t += red[threadIdx.x * 8 + q];
        bf[threadIdx.x] = t;
    }
}

// b2[o] = up_b[o] + sum_h up_wT[h][o] * pout_b[h]       (grid=8, block=256)
__global__ void k_bias_2(const float* __restrict__ up_wT, const float* __restrict__ pout_b,
                         const float* __restrict__ up_b, float* __restrict__ b2) {
    int o = blockIdx.x * 256 + threadIdx.x;
    float s = up_b[o];
    for (int h = 0; h < HID; h++)
        s = fmaf(up_wT[h * 2048 + o], pout_b[h], s);
    b2[o] = s;
}

// T[n][o] = b2[o] + sum_c cb[n][c] * U2c[c][o]          (grid=(256,8))
__global__ void k_table(const float* __restrict__ U2c, const float* __restrict__ cb,
                        const float* __restrict__ b2, float* __restrict__ T) {
    int n = blockIdx.x;
    int o = blockIdx.y * 256 + threadIdx.x;
    float s = b2[o];
    #pragma unroll
    for (int c = 0; c < 32; c++)
        s = fmaf(cb[n * 32 + c], U2c[c * 2048 + o], s);
    T[n * 2048 + o] = s;
}

// ---------------------------------------------------------------------------
// Main: z = x @ WfT + bf, then argmin over 256 codes. 64 tokens/block, grid=256.
__global__ __launch_bounds__(256) void k_zargmin(
    const float* __restrict__ x, const float* __restrict__ WfT,
    const float* __restrict__ bf, const float* __restrict__ cb,
    int* __restrict__ idx_i, float* __restrict__ idx_f) {
    // buf: phase A = x-chunk transposed [128 k][65 pad] (8320 f)
    //      phase B = cb_s [256][36] (9216 f) + cbn [256]
    __shared__ float buf[9472];
    __shared__ float z_s[64 * 36];
    __shared__ float red_d[256];
    __shared__ int   red_i[256];

    int tid  = threadIdx.x;
    int lane = tid & 63;
    int w    = __builtin_amdgcn_readfirstlane(tid >> 6);  // wave id 0..3
    int m0   = blockIdx.x * 64;

    float acc[8];
    #pragma unroll
    for (int j = 0; j < 8; j++) acc[j] = 0.f;

    // ---- phase A: z[token][c], wave w owns c in [8w, 8w+8)
    for (int ch = 0; ch < 16; ch++) {
        // stage 64 tokens x 128 k (transposed, pad 65 -> conflict-free reads)
        #pragma unroll
        for (int j = 0; j < 8; j++) {
            int f = j * 256 + tid;               // float4 id 0..2047
            int r = f >> 5, cq = f & 31;
            float4 v = *(const float4*)(x + (size_t)(m0 + r) * 2048 + ch * 128 + cq * 4);
            buf[(cq * 4 + 0) * 65 + r] = v.x;
            buf[(cq * 4 + 1) * 65 + r] = v.y;
            buf[(cq * 4 + 2) * 65 + r] = v.z;
            buf[(cq * 4 + 3) * 65 + r] = v.w;
        }
        __syncthreads();
        const float* wrow = WfT + (ch * 128) * 32 + w * 8;   // wave-uniform -> s_load
        #pragma unroll 4
        for (int k = 0; k < 128; k++) {
            float xv = buf[k * 65 + lane];
            #pragma unroll
            for (int j = 0; j < 8; j++)
                acc[j] = fmaf(wrow[k * 32 + j], xv, acc[j]);
        }
        __syncthreads();
    }
    #pragma unroll
    for (int j = 0; j < 8; j++)
        z_s[lane * 36 + w * 8 + j] = acc[j] + bf[w * 8 + j];

    // stage codebook into buf rows of 36 (16B-aligned)
    #pragma unroll
    for (int j = 0; j < 8; j++) {
        int f = j * 256 + tid;               // float4 id, 2048 total
        int n = f >> 3, q = f & 7;
        float4 v = *(const float4*)(cb + n * 32 + q * 4);
        buf[n * 36 + q * 4 + 0] = v.x;
        buf[n * 36 + q * 4 + 1] = v.y;
        buf[n * 36 + q * 4 + 2] = v.z;
        buf[n * 36 + q * 4 + 3] = v.w;
    }
    __syncthreads();
    {   // cbn[n] = |cb_n|^2
        float s = 0.f;
        #pragma unroll
        for (int q = 0; q < 8; q++) {
            float4 v = *(const float4*)(&buf[tid * 36 + q * 4]);
            s += v.x * v.x + v.y * v.y + v.z * v.z + v.w * v.w;
        }
        buf[9216 + tid] = s;
    }
    __syncthreads();

    // ---- phase B: token = lane, wave w scans codes [64w, 64w+64)
    float z[32];
    #pragma unroll
    for (int q = 0; q < 8; q++) {
        float4 v = *(const float4*)(&z_s[lane * 36 + q * 4]);
        z[q * 4 + 0] = v.x; z[q * 4 + 1] = v.y; z[q * 4 + 2] = v.z; z[q * 4 + 3] = v.w;
    }
    float bd = 3.4e38f; int bi = 0;
    for (int t = 0; t < 64; t++) {
        int n = w * 64 + t;                   // wave-uniform -> LDS broadcast
        float s = 0.f;
        #pragma unroll
        for (int q = 0; q < 8; q++) {
            float4 v = *(const float4*)(&buf[n * 36 + q * 4]);
            s = fmaf(v.x, z[q * 4 + 0], s);
            s = fmaf(v.y, z[q * 4 + 1], s);
            s = fmaf(v.z, z[q * 4 + 2], s);
            s = fmaf(v.w, z[q * 4 + 3], s);
        }
        float d = fmaf(-2.f, s, buf[9216 + n]);
        if (d < bd) { bd = d; bi = n; }       // strict < : first min wins (np semantics)
    }
    red_d[w * 64 + lane] = bd;
    red_i[w * 64 + lane] = bi;
    __syncthreads();
    if (tid < 64) {
        float d0 = red_d[tid]; int i0 = red_i[tid];
        #pragma unroll
        for (int ww = 1; ww < 4; ww++) {      // ascending wave = ascending code range
            float d1 = red_d[ww * 64 + tid];
            int   i1 = red_i[ww * 64 + tid];
            if (d1 < d0) { d0 = d1; i0 = i1; }
        }
        idx_i[m0 + tid] = i0;
        idx_f[m0 + tid] = (float)i0;
    }
}

// ---------------------------------------------------------------------------
// out[m][:] = clip(T[idx[m]][:], -1, 1);  2 tokens/block, grid=8192
__global__ void k_gather(const float* __restrict__ T, const int* __restrict__ idx_i,
                         float* __restrict__ out, float* __restrict__ loss) {
    int m   = blockIdx.x * 2 + (threadIdx.x >> 7);
    int sub = threadIdx.x & 127;
    int n = idx_i[m];
    const float4* Tr = (const float4*)(T + (size_t)n * 2048);
    float4* Or = (float4*)(out + (size_t)m * 2048);
    #pragma unroll
    for (int j = 0; j < 4; j++) {
        float4 v = Tr[j * 128 + sub];
        v.x = fminf(fmaxf(v.x, -1.f), 1.f);
        v.y = fminf(fmaxf(v.y, -1.f), 1.f);
        v.z = fminf(fmaxf(v.z, -1.f), 1.f);
        v.w = fminf(fmaxf(v.w, -1.f), 1.f);
        Or[j * 128 + sub] = v;
    }
    if (blockIdx.x == 0 && threadIdx.x == 0) *loss = 0.f;
}

// ---------------------------------------------------------------------------
extern "C" void kernel_launch(void* const* d_in, const int* in_sizes, int n_in,
                              void* d_out, int out_size, void* d_ws, size_t ws_size,
                              hipStream_t stream) {
    const float* x      = (const float*)d_in[0];
    const float* down_w = (const float*)d_in[1];
    const float* down_b = (const float*)d_in[2];
    const float* pin_w  = (const float*)d_in[3];
    const float* pin_b  = (const float*)d_in[4];
    const float* cb     = (const float*)d_in[5];
    const float* pout_w = (const float*)d_in[6];
    const float* pout_b = (const float*)d_in[7];
    const float* up_w   = (const float*)d_in[8];
    const float* up_b   = (const float*)d_in[9];

    float* ws    = (float*)d_ws;
    float* up_wT = ws + WS_UPWT;
    float* part  = ws + WS_PART;
    float* WfT   = ws + WS_WFT;
    float* U2c   = ws + WS_U2C;
    float* bf    = ws + WS_BF;
    float* b2    = ws + WS_B2;
    float* T     = ws + WS_T;
    int*   idx   = (int*)(ws + WS_IDX);

    float* out_f  = (float*)d_out;                   // [16384][2048]
    float* idx_f  = out_f + (size_t)TOK * OUTF;      // [16384]
    float* loss_f = idx_f + TOK;                     // [1]

    // precompute fused weights + table
    kt_transpose<<<dim3(32, 64), 256, 0, stream>>>(up_w, up_wT);
    // WfT = (pin_w @ down_w), stored [i][c]
    k_fuse_partial<<<dim3(8, 16), 256, 0, stream>>>(pin_w, down_w, part, HID, 1);
    k_fuse_reduce<<<256, 256, 0, stream>>>(part, WfT, 32, 1);
    k_bias_f<<<1, 256, 0, stream>>>(pin_w, pin_b, down_b, bf);
    // U2c = (up_w @ pout_w)^T, stored [c][o]
    k_fuse_partial<<<dim3(8, 16), 256, 0, stream>>>(pout_w, up_wT, part, 1, CBD);
    k_fuse_reduce<<<256, 256, 0, stream>>>(part, U2c, 1, 2048);
    k_bias_2<<<8, 256, 0, stream>>>(up_wT, pout_b, up_b, b2);
    k_table<<<dim3(256, 8), 256, 0, stream>>>(U2c, cb, b2, T);

    // main: z + argmin, then gather table rows
    k_zargmin<<<256, 256, 0, stream>>>(x, WfT, bf, cb, idx, idx_f);
    k_gather<<<8192, 256, 0, stream>>>(T, idx, out_f, loss_f);
}

// Round 3
// 457.941 us; speedup vs baseline: 1.3108x; 1.3108x over previous
//
#include <hip/hip_runtime.h>

// Problem dims
#define TOK   16384   // B*S
#define INFT  2048
#define HID   1024
#define CBD   32
#define NC    256
#define OUTF  2048
#define KB    4       // k-split chunks for z GEMM (512 k each)

// ---------------------------------------------------------------------------
// ws layout (float offsets) — total ~15.4 MB
//  up_wT   : [1024][2048]           @ 0          (2,097,152)   dead after k_bias2_part
//  zpart   : [4][16384][32]         @ 0          (2,097,152)   ALIASES up_wT (stream-ordered)
//  part    : [16][32][2048]         @ 2097152    (1,048,576)
//  WfT     : [2048][32] (k-major)   @ 3145728    (65,536)
//  U2c     : [32][2048] (c-major)   @ 3211264    (65,536)
//  bf      : [32]                   @ 3276800
//  bpart   : [16][2048]             @ 3278880    (32,768)
//  T       : [256][2048]            @ 3311648    (524,288)
//  idx     : [16384] int            @ 3835936
#define WS_UPWT   0
#define WS_ZPART  0
#define WS_PART   2097152
#define WS_WFT    3145728
#define WS_U2C    3211264
#define WS_BF     3276800
#define WS_BPART  3278880
#define WS_T      3311648
#define WS_IDX    3835936

// ---------------------------------------------------------------------------
// Transpose up_w [2048][1024] -> up_wT [1024][2048]
__global__ void kt_transpose(const float* __restrict__ up_w, float* __restrict__ up_wT) {
    __shared__ float tile[32][33];
    int h0 = blockIdx.x * 32;            // over HID
    int o0 = blockIdx.y * 32;            // over OUTF
    int tx = threadIdx.x & 31, ty = threadIdx.x >> 5;   // 32x8
    #pragma unroll
    for (int j = 0; j < 32; j += 8)
        tile[ty + j][tx] = up_w[(o0 + ty + j) * HID + h0 + tx];
    __syncthreads();
    #pragma unroll
    for (int j = 0; j < 32; j += 8)
        up_wT[(h0 + ty + j) * OUTF + o0 + tx] = tile[tx][ty + j];
}

// ---------------------------------------------------------------------------
// Fused weight partial: part[kc][c][2048] = sum_{k in chunk} lhs(c,k) * rhs[k][i]
__global__ void k_fuse_partial(const float* __restrict__ lhs, const float* __restrict__ rhs,
                               float* __restrict__ part, int lhsSC, int lhsSK) {
    int i  = blockIdx.x * 256 + threadIdx.x;
    int k0 = blockIdx.y * 64;
    float acc[32];
    #pragma unroll
    for (int c = 0; c < 32; c++) acc[c] = 0.f;
    #pragma unroll 4
    for (int j = 0; j < 64; j++) {
        float xv = rhs[(k0 + j) * 2048 + i];
        #pragma unroll
        for (int c = 0; c < 32; c++)
            acc[c] = fmaf(lhs[c * lhsSC + (k0 + j) * lhsSK], xv, acc[c]);
    }
    #pragma unroll
    for (int c = 0; c < 32; c++)
        part[(blockIdx.y * 32 + c) * 2048 + i] = acc[c];
}

// Reduce 16 partials -> outw[i*outSI + c*outSC]
__global__ void k_fuse_reduce(const float* __restrict__ part, float* __restrict__ outw,
                              int outSI, int outSC) {
    int f = blockIdx.x * 256 + threadIdx.x;   // 0..65535
    int i = f & 2047, c = f >> 11;
    float s = 0.f;
    #pragma unroll
    for (int b = 0; b < 16; b++) s += part[b * 65536 + c * 2048 + i];
    outw[i * outSI + c * outSC] = s;
}

// bf[c] = pin_b[c] + sum_k pin_w[c][k] * down_b[k]      (grid=1, block=256)
__global__ void k_bias_f(const float* __restrict__ pin_w, const float* __restrict__ pin_b,
                         const float* __restrict__ down_b, float* __restrict__ bf) {
    __shared__ float red[256];
    int c = threadIdx.x >> 3, seg = threadIdx.x & 7;
    float s = 0.f;
    #pragma unroll 8
    for (int k = seg * 128; k < seg * 128 + 128; k++)
        s = fmaf(pin_w[c * HID + k], down_b[k], s);
    red[threadIdx.x] = s;
    __syncthreads();
    if (threadIdx.x < 32) {
        float t = pin_b[threadIdx.x];
        #pragma unroll
        for (int q = 0; q < 8; q++) t += red[threadIdx.x * 8 + q];
        bf[threadIdx.x] = t;
    }
}

// bpart[hc][o] = (hc==0 ? up_b[o] : 0) + sum_{h in chunk} up_wT[h][o]*pout_b[h]
// grid (8, 16), block 256
__global__ void k_bias2_part(const float* __restrict__ up_wT, const float* __restrict__ pout_b,
                             const float* __restrict__ up_b, float* __restrict__ bpart) {
    int o  = blockIdx.x * 256 + threadIdx.x;
    int hc = blockIdx.y;
    float s = (hc == 0) ? up_b[o] : 0.f;
    #pragma unroll 8
    for (int h = hc * 64; h < hc * 64 + 64; h++)
        s = fmaf(up_wT[h * 2048 + o], pout_b[h], s);
    bpart[hc * 2048 + o] = s;
}

// T[n][o] = sum_hc bpart[hc][o] + sum_c cb[n][c] * U2c[c][o]     grid (256, 8)
__global__ void k_table(const float* __restrict__ U2c, const float* __restrict__ cb,
                        const float* __restrict__ bpart, float* __restrict__ T) {
    int n = blockIdx.x;
    int o = blockIdx.y * 256 + threadIdx.x;
    float s = 0.f;
    #pragma unroll
    for (int hc = 0; hc < 16; hc++) s += bpart[hc * 2048 + o];
    #pragma unroll
    for (int c = 0; c < 32; c++)
        s = fmaf(cb[n * 32 + c], U2c[c * 2048 + o], s);
    T[n * 2048 + o] = s;
}

// ---------------------------------------------------------------------------
// z partial GEMM: grid (256, KB). Block = 64 tokens x 512 k.
// Wave w owns k-quarter [w*32, w*32+32) of each 128-k chunk, all 32 c-columns.
// zpart[kb][tok][c] = sum_{k in chunk} x[tok][k] * WfT[k][c]
__global__ __launch_bounds__(256) void k_zpart(const float* __restrict__ x,
                                               const float* __restrict__ WfT,
                                               float* __restrict__ zpart) {
    // staging: 64 tokens x 32 float4 (128 k), stride 33 f4 -> no row overlap.
    // also reused (as float[4*64*33] = 8448) for the cross-wave reduce.
    __shared__ float4 xs[64 * 33 + 1];
    int tid  = threadIdx.x;
    int lane = tid & 63;                                  // token within block
    int w    = __builtin_amdgcn_readfirstlane(tid >> 6);  // k-quarter 0..3
    int m0   = blockIdx.x * 64;
    int kb   = blockIdx.y;

    float acc[32];
    #pragma unroll
    for (int c = 0; c < 32; c++) acc[c] = 0.f;

    for (int sc = 0; sc < 4; sc++) {
        int k0 = kb * 512 + sc * 128;
        // stage 64 tokens x 128 floats; coalesced 16B/lane
        #pragma unroll
        for (int j = 0; j < 8; j++) {
            int f = j * 256 + tid;            // 0..2047
            int t = f >> 5, q = f & 31;
            xs[t * 33 + q] = *(const float4*)(x + (size_t)(m0 + t) * 2048 + k0 + q * 4);
        }
        __syncthreads();
        const float* wr = WfT + (size_t)(k0 + w * 32) * 32;   // wave-uniform -> s_load
        #pragma unroll 2
        for (int j = 0; j < 8; j++) {
            float4 xv = xs[lane * 33 + w * 8 + j];
            #pragma unroll
            for (int c = 0; c < 32; c++) {
                acc[c] = fmaf(wr[(j * 4 + 0) * 32 + c], xv.x, acc[c]);
                acc[c] = fmaf(wr[(j * 4 + 1) * 32 + c], xv.y, acc[c]);
                acc[c] = fmaf(wr[(j * 4 + 2) * 32 + c], xv.z, acc[c]);
                acc[c] = fmaf(wr[(j * 4 + 3) * 32 + c], xv.w, acc[c]);
            }
        }
        __syncthreads();
    }

    // deterministic cross-wave reduce: rp[w][t][c], stride 33 (bank = (t+c)%32, 2-way free)
    float* rp = (float*)xs;
    #pragma unroll
    for (int c = 0; c < 32; c++)
        rp[(w * 64 + lane) * 33 + c] = acc[c];
    __syncthreads();
    int t  = tid >> 2;
    int cq = (tid & 3) * 8;
    float s[8];
    #pragma unroll
    for (int j = 0; j < 8; j++) {
        float v = rp[(0 * 64 + t) * 33 + cq + j];
        #pragma unroll
        for (int ww = 1; ww < 4; ww++) v += rp[(ww * 64 + t) * 33 + cq + j];
        s[j] = v;
    }
    float* zp = zpart + ((size_t)kb * TOK + m0 + t) * 32 + cq;
    *(float4*)zp       = make_float4(s[0], s[1], s[2], s[3]);
    *(float4*)(zp + 4) = make_float4(s[4], s[5], s[6], s[7]);
}

// ---------------------------------------------------------------------------
// Reduce zpart + bias, then argmin over 256 codes. 64 tokens/block, grid=256.
__global__ __launch_bounds__(256) void k_zred(
    const float* __restrict__ zpart, const float* __restrict__ bf,
    const float* __restrict__ cb,
    int* __restrict__ idx_i, float* __restrict__ idx_f) {
    __shared__ float z_s[64 * 36];
    __shared__ float cbs[256 * 36];
    __shared__ float cbn[256];
    __shared__ float red_d[256];
    __shared__ int   red_i[256];

    int tid  = threadIdx.x;
    int lane = tid & 63;
    int w    = __builtin_amdgcn_readfirstlane(tid >> 6);
    int m0   = blockIdx.x * 64;

    // reduce KB partials + bias -> z_s  (coalesced reads)
    #pragma unroll
    for (int i = 0; i < 8; i++) {
        int f = i * 256 + tid;                // 0..2047
        int t = f >> 5, c = f & 31;
        float s = bf[c];
        #pragma unroll
        for (int kb = 0; kb < KB; kb++)
            s += zpart[((size_t)kb * TOK + m0 + t) * 32 + c];
        z_s[t * 36 + c] = s;
    }
    // stage codebook, rows of 36 (16B aligned)
    #pragma unroll
    for (int j = 0; j < 8; j++) {
        int f = j * 256 + tid;                // float4 id, 2048 total
        int n = f >> 3, q = f & 7;
        float4 v = *(const float4*)(cb + n * 32 + q * 4);
        cbs[n * 36 + q * 4 + 0] = v.x;
        cbs[n * 36 + q * 4 + 1] = v.y;
        cbs[n * 36 + q * 4 + 2] = v.z;
        cbs[n * 36 + q * 4 + 3] = v.w;
    }
    __syncthreads();
    {   // cbn[n] = |cb_n|^2
        float s = 0.f;
        #pragma unroll
        for (int q = 0; q < 8; q++) {
            float4 v = *(const float4*)(&cbs[tid * 36 + q * 4]);
            s += v.x * v.x + v.y * v.y + v.z * v.z + v.w * v.w;
        }
        cbn[tid] = s;
    }
    __syncthreads();

    // token = lane, wave w scans codes [64w, 64w+64)
    float z[32];
    #pragma unroll
    for (int q = 0; q < 8; q++) {
        float4 v = *(const float4*)(&z_s[lane * 36 + q * 4]);
        z[q * 4 + 0] = v.x; z[q * 4 + 1] = v.y; z[q * 4 + 2] = v.z; z[q * 4 + 3] = v.w;
    }
    float bd = 3.4e38f; int bi = 0;
    for (int t = 0; t < 64; t++) {
        int n = w * 64 + t;                   // wave-uniform -> LDS broadcast
        float s = 0.f;
        #pragma unroll
        for (int q = 0; q < 8; q++) {
            float4 v = *(const float4*)(&cbs[n * 36 + q * 4]);
            s = fmaf(v.x, z[q * 4 + 0], s);
            s = fmaf(v.y, z[q * 4 + 1], s);
            s = fmaf(v.z, z[q * 4 + 2], s);
            s = fmaf(v.w, z[q * 4 + 3], s);
        }
        float d = fmaf(-2.f, s, cbn[n]);
        if (d < bd) { bd = d; bi = n; }       // strict < : first min wins (np semantics)
    }
    red_d[w * 64 + lane] = bd;
    red_i[w * 64 + lane] = bi;
    __syncthreads();
    if (tid < 64) {
        float d0 = red_d[tid]; int i0 = red_i[tid];
        #pragma unroll
        for (int ww = 1; ww < 4; ww++) {      // ascending wave = ascending code range
            float d1 = red_d[ww * 64 + tid];
            int   i1 = red_i[ww * 64 + tid];
            if (d1 < d0) { d0 = d1; i0 = i1; }
        }
        idx_i[m0 + tid] = i0;
        idx_f[m0 + tid] = (float)i0;
    }
}

// ---------------------------------------------------------------------------
// out[m][:] = clip(T[idx[m]][:], -1, 1);  2 tokens/block, grid=8192
__global__ void k_gather(const float* __restrict__ T, const int* __restrict__ idx_i,
                         float* __restrict__ out, float* __restrict__ loss) {
    int m   = blockIdx.x * 2 + (threadIdx.x >> 7);
    int sub = threadIdx.x & 127;
    int n = idx_i[m];
    const float4* Tr = (const float4*)(T + (size_t)n * 2048);
    float4* Or = (float4*)(out + (size_t)m * 2048);
    #pragma unroll
    for (int j = 0; j < 4; j++) {
        float4 v = Tr[j * 128 + sub];
        v.x = fminf(fmaxf(v.x, -1.f), 1.f);
        v.y = fminf(fmaxf(v.y, -1.f), 1.f);
        v.z = fminf(fmaxf(v.z, -1.f), 1.f);
        v.w = fminf(fmaxf(v.w, -1.f), 1.f);
        Or[j * 128 + sub] = v;
    }
    if (blockIdx.x == 0 && threadIdx.x == 0) *loss = 0.f;
}

// ---------------------------------------------------------------------------
extern "C" void kernel_launch(void* const* d_in, const int* in_sizes, int n_in,
                              void* d_out, int out_size, void* d_ws, size_t ws_size,
                              hipStream_t stream) {
    const float* x      = (const float*)d_in[0];
    const float* down_w = (const float*)d_in[1];
    const float* down_b = (const float*)d_in[2];
    const float* pin_w  = (const float*)d_in[3];
    const float* pin_b  = (const float*)d_in[4];
    const float* cb     = (const float*)d_in[5];
    const float* pout_w = (const float*)d_in[6];
    const float* pout_b = (const float*)d_in[7];
    const float* up_w   = (const float*)d_in[8];
    const float* up_b   = (const float*)d_in[9];

    float* ws    = (float*)d_ws;
    float* up_wT = ws + WS_UPWT;
    float* zpart = ws + WS_ZPART;   // aliases up_wT (stream-ordered: written after last use)
    float* part  = ws + WS_PART;
    float* WfT   = ws + WS_WFT;
    float* U2c   = ws + WS_U2C;
    float* bf    = ws + WS_BF;
    float* bpart = ws + WS_BPART;
    float* T     = ws + WS_T;
    int*   idx   = (int*)(ws + WS_IDX);

    float* out_f  = (float*)d_out;                   // [16384][2048]
    float* idx_f  = out_f + (size_t)TOK * OUTF;      // [16384]
    float* loss_f = idx_f + TOK;                     // [1]

    // precompute fused weights + table
    kt_transpose<<<dim3(32, 64), 256, 0, stream>>>(up_w, up_wT);
    // WfT = (pin_w @ down_w), stored [k][c]
    k_fuse_partial<<<dim3(8, 16), 256, 0, stream>>>(pin_w, down_w, part, HID, 1);
    k_fuse_reduce<<<256, 256, 0, stream>>>(part, WfT, 32, 1);
    k_bias_f<<<1, 256, 0, stream>>>(pin_w, pin_b, down_b, bf);
    // U2c = (up_w @ pout_w)^T, stored [c][o]
    k_fuse_partial<<<dim3(8, 16), 256, 0, stream>>>(pout_w, up_wT, part, 1, CBD);
    k_fuse_reduce<<<256, 256, 0, stream>>>(part, U2c, 1, 2048);
    k_bias2_part<<<dim3(8, 16), 256, 0, stream>>>(up_wT, pout_b, up_b, bpart);
    k_table<<<dim3(256, 8), 256, 0, stream>>>(U2c, cb, bpart, T);

    // main: z partials (high occupancy), reduce+argmin, gather
    k_zpart<<<dim3(256, KB), 256, 0, stream>>>(x, WfT, zpart);
    k_zred<<<256, 256, 0, stream>>>(zpart, bf, cb, idx, idx_f);
    k_gather<<<8192, 256, 0, stream>>>(T, idx, out_f, loss_f);
}